// Round 18
// baseline (221.093 us; speedup 1.0000x reference)
//
#include <hip/hip_runtime.h>
#include <hip/hip_bf16.h>

#define S_LEN 4096
#define EMB   768
#define NH    12
#define DH    64
#define NCHUNK 4
#define CKL2   10         // chunk keys = 1024

#define LOG2E 1.44269504088896f

// finite sentinel instead of -INFINITY: safe under fast-math builds
#define NEG_BIG (-1e30f)

// HW 2^x (v_exp_f32); __exp2f does not exist in HIP device code
#define EXP2F(x) __builtin_amdgcn_exp2f(x)

using bf16x8 = __attribute__((ext_vector_type(8))) short;
using bf16x4 = __attribute__((ext_vector_type(4))) short;
using f32x4  = __attribute__((ext_vector_type(4))) float;

__device__ __forceinline__ short f2bf(float f) {
    __hip_bfloat16 h = __float2bfloat16(f);
    short s; __builtin_memcpy(&s, &h, 2); return s;
}
__device__ __forceinline__ float bf2f(short s) {
    __hip_bfloat16 h; __builtin_memcpy(&h, &s, 2);
    return __bfloat162float(h);
}

// pack two f32 -> two bf16 (RNE) in ONE instruction (no builtin on gfx950)
__device__ __forceinline__ unsigned cvt_pk_bf16(float a, float b) {
    unsigned r;
    asm("v_cvt_pk_bf16_f32 %0, %1, %2" : "=v"(r) : "v"(a), "v"(b));
    return r;
}

// async global->LDS, 16B per lane; lds dest = uniform base + lane*16
__device__ __forceinline__ void gld_lds16(const void* g, void* l) {
    __builtin_amdgcn_global_load_lds(
        (const __attribute__((address_space(1))) unsigned int*)g,
        (__attribute__((address_space(3))) unsigned int*)l, 16, 0, 0);
}

__device__ __forceinline__ void cvt8(const float* s, short* d, int i) {
    const float4 a = ((const float4*)s)[i * 2];
    const float4 b = ((const float4*)s)[i * 2 + 1];
    bf16x8 o;
    o[0] = f2bf(a.x); o[1] = f2bf(a.y); o[2] = f2bf(a.z); o[3] = f2bf(a.w);
    o[4] = f2bf(b.x); o[5] = f2bf(b.y); o[6] = f2bf(b.z); o[7] = f2bf(b.w);
    ((bf16x8*)d)[i] = o;
}

// ---------------------------------------------------------------------------
// Kernel 0a/0b: fp32 -> bf16 converts
// ---------------------------------------------------------------------------
__global__ __launch_bounds__(256) void cvt_bf16(
    const float* __restrict__ s, short* __restrict__ d, int n8)
{
    const int i = blockIdx.x * 256 + threadIdx.x;
    if (i < n8) cvt8(s, d, i);
}

__global__ __launch_bounds__(256) void cvt3_bf16(
    const float* __restrict__ x,  short* __restrict__ xb,  int n8x,
    const float* __restrict__ wq, short* __restrict__ wqb, int n8q,
    const float* __restrict__ wo, short* __restrict__ wob, int n8o)
{
    int i = blockIdx.x * 256 + threadIdx.x;
    if (i < n8x) { cvt8(x, xb, i); return; }
    i -= n8x;
    if (i < n8q) { cvt8(wq, wqb, i); return; }
    i -= n8q;
    if (i < n8o) cvt8(wo, wob, i);
}

// ---------------------------------------------------------------------------
// Kernel 1: QKV projection — r14 (PASSED, 218.7us total config):
// 64x128 tiles, 1152 blocks (4.5/CU). gld_lds staging, XCD banding
// (1152 = 8 x 144), coalesced epilogues. Per wave: 32m x 64n, acc[2][4].
// Q pre-scaled by log2(e) so flash uses exp2 (1 instr).
// ---------------------------------------------------------------------------
__global__ __launch_bounds__(256) void qkv_gemm(
    const short* __restrict__ Xb, const short* __restrict__ Wb,
    const float* __restrict__ Bias,
    short* __restrict__ Qw, short* __restrict__ Kw, short* __restrict__ Vt)
{
    __shared__ __align__(16) short SMEM[64 * 64 + 128 * 64];  // As | Bs (24KB)
    short* As = SMEM;                     // [64 m][64 k]
    short* Bs = SMEM + 64 * 64;           // [128 n][64 k]

    // XCD-chunked decode: 1152 = 8 chunks of 144 = 8 m-rows x 18 n
    const int flat = blockIdx.x;
    const int swz = (flat & 7) * 144 + (flat >> 3);
    const int m0 = (swz / 18) * 64;
    const int n0 = (swz % 18) * 128;
    const int t = threadIdx.x;
    const int lane = t & 63, wave = t >> 6;
    const int quad = lane >> 4, l16 = lane & 15;
    const int wm = (wave >> 1) * 32, wn = (wave & 1) * 64;
    const int srow = lane >> 3, scol = (lane & 7) * 8;

    f32x4 acc[2][4] = {};

    for (int k0 = 0; k0 < EMB; k0 += 64) {
        #pragma unroll
        for (int qd = 0; qd < 2; qd++) {        // A: 8 chunks (64 rows)
            const int chunk = wave * 2 + qd;
            const int row = chunk * 8 + srow;
            gld_lds16(&Xb[(size_t)(m0 + row) * EMB + k0 + scol], &As[chunk * 512]);
        }
        #pragma unroll
        for (int qd = 0; qd < 4; qd++) {        // B: 16 chunks (128 rows)
            const int chunk = wave * 4 + qd;
            const int row = chunk * 8 + srow;
            gld_lds16(&Wb[(size_t)(n0 + row) * EMB + k0 + scol], &Bs[chunk * 512]);
        }
        __syncthreads();

        #pragma unroll
        for (int kb = 0; kb < 2; kb++) {
            bf16x8 af[2], bfr[4];
            #pragma unroll
            for (int i = 0; i < 2; i++)
                af[i] = *(const bf16x8*)&As[(wm + i * 16 + l16) * 64 + kb * 32 + quad * 8];
            #pragma unroll
            for (int j = 0; j < 4; j++)
                bfr[j] = *(const bf16x8*)&Bs[(wn + j * 16 + l16) * 64 + kb * 32 + quad * 8];
            #pragma unroll
            for (int i = 0; i < 2; i++)
                #pragma unroll
                for (int j = 0; j < 4; j++)
                    acc[i][j] = __builtin_amdgcn_mfma_f32_16x16x32_bf16(
                        af[i], bfr[j], acc[i][j], 0, 0, 0);
        }
        __syncthreads();
    }

    const int part = n0 / EMB;           // block-uniform: 0=Q 1=K 2=V

    if (part < 2) {
        // Q/K: LDS [m 64][n 128] restage -> coalesced 16B stores.
        const float qs = (part == 0) ? LOG2E : 1.0f;
        short* dst = (part == 0) ? Qw : Kw;
        #pragma unroll
        for (int j = 0; j < 4; j++) {
            const int nl = wn + j * 16 + l16;
            const float bias = Bias[n0 + nl];
            #pragma unroll
            for (int i = 0; i < 2; i++)
                #pragma unroll
                for (int r = 0; r < 4; r++)
                    SMEM[(wm + i * 16 + quad * 4 + r) * 128 + nl] =
                        f2bf((acc[i][j][r] + bias) * qs);
        }
        __syncthreads();
        #pragma unroll
        for (int c = t; c < 1024; c += 256) {    // 64 m-rows x 16 8-n chunks
            const int m = c >> 4, noff = (c & 15) * 8;
            const int r768 = (n0 + noff) % EMB;  // head-aligned: noff%64 in 8s
            const int h = r768 >> 6, d = r768 & 63;
            *(bf16x8*)&dst[((size_t)h * S_LEN + m0 + m) * DH + d] =
                *(const bf16x8*)&SMEM[m * 128 + noff];
        }
    } else {
        // V: transpose C-tile through LDS T[128 n][64 m], coalesced Vt rows.
        #pragma unroll
        for (int j = 0; j < 4; j++) {
            const int nl = wn + j * 16 + l16;
            const float bias = Bias[n0 + nl];
            #pragma unroll
            for (int i = 0; i < 2; i++) {
                short4 v;
                v.x = f2bf(acc[i][j][0] + bias);
                v.y = f2bf(acc[i][j][1] + bias);
                v.z = f2bf(acc[i][j][2] + bias);
                v.w = f2bf(acc[i][j][3] + bias);
                *(short4*)&SMEM[nl * 64 + wm + i * 16 + quad * 4] = v;
            }
        }
        __syncthreads();
        const int vrow0 = n0 - 2 * EMB;          // Vt row base = h*64+d = r768
        #pragma unroll
        for (int c = t; c < 1024; c += 256) {    // 128 rows x 8 8-m chunks
            const int row = c >> 3, off = (c & 7) * 8;
            *(bf16x8*)&Vt[(size_t)(vrow0 + row) * S_LEN + m0 + off] =
                *(const bf16x8*)&SMEM[row * 64 + off];
        }
    }
}

// ---------------------------------------------------------------------------
// Kernel 2a: split-K flash partial — r11/r16 VERBATIM (PASSED, ~49.5us).
// Weight-sorted 1-D grid, one job per block; __launch_bounds__(256,3).
// r17 bisect: (256,5) ALONE reproduces absmax 0.738 bit-identical to r15 —
// tightening min-waves miscompiles this gld_lds+setprio kernel on this
// toolchain despite no semantic mechanism. KEEP (256,3). Ledger lesson:
// launch_bounds occupancy hints are codegen-affecting and correctness-risky;
// verify in isolation.
// ---------------------------------------------------------------------------
__global__ __launch_bounds__(256, 3) void flash_partial(
    const short* __restrict__ Qw, const short* __restrict__ Kw,
    const short* __restrict__ Vt,
    short* __restrict__ Opart, float* __restrict__ Mpart,
    float* __restrict__ Lpart)
{
    // ---- weight-sorted job decode (960 jobs; audited complete/disjoint):
    int qt, h, kc;
    {
        const int job = blockIdx.x;
        if (job < 624) {
            h = job / 52;
            const int r = job % 52;
            if (r < 25)      { kc = 0; qt = 7 + r; }
            else if (r < 42) { kc = 1; qt = 15 + (r - 25); }
            else if (r < 51) { kc = 2; qt = 23 + (r - 42); }
            else             { kc = 3; qt = 31; }
        } else {
            const int j2 = job - 624;
            const int w = 7 - j2 / 48;
            const int r = j2 % 48;
            h = r >> 2; kc = r & 3;
            qt = 8 * kc + w - 1;
        }
    }
    const int q0  = qt * 128;
    const int ks0 = kc << CKL2;
    const int KIT = (1 << CKL2) / 128;   // 8
    const int nk = min(KIT, (q0 >> 7) - KIT * kc + 1);

    // K tile [128 k][64 d] 16KB | V tile [64 d][128 k] 16KB (single buffer)
    __shared__ __align__(16) short SMEM[128 * 64 + 64 * 128];   // 32 KB
    short* Ks = SMEM;
    short* Vs = SMEM + 128 * 64;

    const int t = threadIdx.x;
    const int lane = t & 63, wave = t >> 6;
    const int quad = lane >> 4, l16 = lane & 15;
    const int qw0 = q0 + wave * 32;          // this wave's 32 q rows
    const int swk = (l16 & 7) << 4;          // K read swizzle (bytes, 3 bits)
    const int swv = l16 << 4;                // V read swizzle (bytes, 4 bits)

    const short* Kh = Kw + (size_t)h * S_LEN * DH;
    const short* Vh = Vt + (size_t)h * DH * S_LEN;

    // staging geometry (r3): pre-swizzled global source, linear LDS dest
    const int krow = lane >> 3;                  // K: row-in-chunk 0..7
    const int kcol = ((lane & 7) ^ krow) << 3;   // pre-swizzled col (shorts)
    const int vrow = lane >> 4;                  // V: row-in-chunk 0..3
    const int vsc  = lane & 15;                  // 16B slot in 256B row

    bf16x8 qf[2][2];
    #pragma unroll
    for (int i = 0; i < 2; i++)
        #pragma unroll
        for (int kb = 0; kb < 2; kb++)
            qf[i][kb] = *(const bf16x8*)
                &Qw[((size_t)h * S_LEN + qw0 + i * 16 + l16) * DH + kb * 32 + quad * 8];

    // constant ones-row A-fragment -> row sum via MFMA (5th PV block)
    bf16x8 vfc;
    {
        const short o1 = (l16 == 0) ? (short)0x3F80 : (short)0;
        #pragma unroll
        for (int c = 0; c < 8; c++) vfc[c] = o1;
    }

    float m_i[2] = {NEG_BIG, NEG_BIG};
    f32x4 o_acc[2][5] = {};                  // [i][4] = ones-row -> sum(p)

    for (int kt = 0; kt < nk; kt++) {
        const int k0 = ks0 + kt * 128;

        __syncthreads();                     // prev tile's readers done
        #pragma unroll
        for (int i = 0; i < 4; i++) {
            const int ck = wave * 4 + i;                 // chunk 0..15
            const int rk = ck * 8 + krow;                // K tile row (key)
            gld_lds16(&Kh[(size_t)(k0 + rk) * DH + kcol], &Ks[ck * 512]);
            const int rv = ck * 4 + vrow;                // V tile row (d)
            const int vcol = (vsc ^ (rv & 15)) << 3;
            gld_lds16(&Vh[(size_t)rv * S_LEN + k0 + vcol], &Vs[ck * 512]);
        }
        __syncthreads();                     // drains vmcnt: data landed

        const bool maskn = (k0 + 127 > q0);
        #pragma unroll
        for (int sub = 0; sub < 2; sub++) {
            const int kbase = k0 + sub * 64;
            if (maskn && kbase > qw0 + 31) continue;          // wave masked
            const bool a0 = !(maskn && kbase > qw0 + 15);     // frag0 active

            // ---- QK^T: sfT[i][bb][r] = score(key=kbase+bb*16+quad*4+r,
            //                                  q=qw0+i*16+l16)
            f32x4 sfT[2][4];
            __builtin_amdgcn_s_setprio(1);
            #pragma unroll
            for (int bb = 0; bb < 4; bb++) {
                const int row = (sub * 4 + bb) * 16 + l16;
                bf16x8 kf[2];
                #pragma unroll
                for (int kb = 0; kb < 2; kb++)
                    kf[kb] = *(const bf16x8*)((const char*)Ks
                        + row * 128 + ((kb * 64 + quad * 16) ^ swk));
                sfT[1][bb] = f32x4{};
                #pragma unroll
                for (int kb = 0; kb < 2; kb++)
                    sfT[1][bb] = __builtin_amdgcn_mfma_f32_16x16x32_bf16(
                        kf[kb], qf[1][kb], sfT[1][bb], 0, 0, 0);
                if (a0) {
                    sfT[0][bb] = f32x4{};
                    #pragma unroll
                    for (int kb = 0; kb < 2; kb++)
                        sfT[0][bb] = __builtin_amdgcn_mfma_f32_16x16x32_bf16(
                            kf[kb], qf[0][kb], sfT[0][bb], 0, 0, 0);
                }
            }
            __builtin_amdgcn_s_setprio(0);

            if (maskn) {
                #pragma unroll
                for (int i = 0; i < 2; i++) {
                    if (i == 0 && !a0) continue;
                    const int qg = qw0 + i * 16 + l16;
                    #pragma unroll
                    for (int bb = 0; bb < 4; bb++)
                        #pragma unroll
                        for (int r = 0; r < 4; r++)
                            if (kbase + bb * 16 + quad * 4 + r > qg)
                                sfT[i][bb][r] = NEG_BIG;
                }
            }

            // ---- online softmax per fragment, defer-max (T13, THR=8 log2)
            #pragma unroll
            for (int i = 0; i < 2; i++) {
                if (i == 0 && !a0) continue;
                float mx = sfT[i][0][0];
                #pragma unroll
                for (int bb = 0; bb < 4; bb++)
                    #pragma unroll
                    for (int r = 0; r < 4; r++) mx = fmaxf(mx, sfT[i][bb][r]);
                mx = fmaxf(mx, __shfl_xor(mx, 16, 64));
                mx = fmaxf(mx, __shfl_xor(mx, 32, 64));
                if (!__all(mx <= m_i[i] + 8.0f)) {
                    const float mnew = fmaxf(m_i[i], mx);
                    const float alpha = EXP2F(m_i[i] - mnew);
                    m_i[i] = mnew;
                    #pragma unroll
                    for (int db = 0; db < 5; db++) o_acc[i][db] *= alpha;
                }
                #pragma unroll
                for (int bb = 0; bb < 4; bb++)
                    #pragma unroll
                    for (int r = 0; r < 4; r++)
                        sfT[i][bb][r] = EXP2F(sfT[i][bb][r] - m_i[i]);
            }

            // ---- PV: full-K=32 MFMA; V fragment shared by both q-frags
            __builtin_amdgcn_s_setprio(1);
            #pragma unroll
            for (int bp = 0; bp < 2; bp++) {
                bf16x8 pf[2];
                #pragma unroll
                for (int i = 0; i < 2; i++) {
                    if (i == 0 && !a0) continue;
                    int4 pv;
                    pv.x = (int)cvt_pk_bf16(sfT[i][2 * bp][0],     sfT[i][2 * bp][1]);
                    pv.y = (int)cvt_pk_bf16(sfT[i][2 * bp][2],     sfT[i][2 * bp][3]);
                    pv.z = (int)cvt_pk_bf16(sfT[i][2 * bp + 1][0], sfT[i][2 * bp + 1][1]);
                    pv.w = (int)cvt_pk_bf16(sfT[i][2 * bp + 1][2], sfT[i][2 * bp + 1][3]);
                    pf[i] = __builtin_bit_cast(bf16x8, pv);
                }
                const int colb = (sub * 2 + bp) * 64 + quad * 8;  // lo byte col
                #pragma unroll
                for (int db = 0; db < 4; db++) {
                    const char* vb = (const char*)Vs + (db * 16 + l16) * 256;
                    const int2 lo2 = *(const int2*)(vb + (colb ^ swv));
                    const int2 hi2 = *(const int2*)(vb + ((colb + 32) ^ swv));
                    int4 vi; vi.x = lo2.x; vi.y = lo2.y; vi.z = hi2.x; vi.w = hi2.y;
                    const bf16x8 vf = __builtin_bit_cast(bf16x8, vi);
                    o_acc[1][db] = __builtin_amdgcn_mfma_f32_16x16x32_bf16(
                        vf, pf[1], o_acc[1][db], 0, 0, 0);
                    if (a0)
                        o_acc[0][db] = __builtin_amdgcn_mfma_f32_16x16x32_bf16(
                            vf, pf[0], o_acc[0][db], 0, 0, 0);
                }
                o_acc[1][4] = __builtin_amdgcn_mfma_f32_16x16x32_bf16(
                    vfc, pf[1], o_acc[1][4], 0, 0, 0);
                if (a0)
                    o_acc[0][4] = __builtin_amdgcn_mfma_f32_16x16x32_bf16(
                        vfc, pf[0], o_acc[0][4], 0, 0, 0);
            }
            __builtin_amdgcn_s_setprio(0);
        }
    }

    const size_t slab = ((size_t)h * NCHUNK + kc) * S_LEN;

    #pragma unroll
    for (int i = 0; i < 2; i++)
        if (quad == 0) {
            const int q = qw0 + i * 16 + l16;
            Mpart[slab + q] = m_i[i];
            Lpart[slab + q] = o_acc[i][4][0];      // sum(p) from ones-row
        }

    __syncthreads();
    #pragma unroll
    for (int i = 0; i < 2; i++)
        #pragma unroll
        for (int db = 0; db < 4; db++) {
            short4 pk4;
            pk4.x = f2bf(o_acc[i][db][0]); pk4.y = f2bf(o_acc[i][db][1]);
            pk4.z = f2bf(o_acc[i][db][2]); pk4.w = f2bf(o_acc[i][db][3]);
            *(short4*)&SMEM[(wave * 32 + i * 16 + l16) * 72 + db * 16 + quad * 4] = pk4;
        }
    __syncthreads();
    #pragma unroll
    for (int c = t; c < 1024; c += 256) {          // 128 rows x 8 chunks
        const int row = c >> 3, off = (c & 7) * 8;
        *(bf16x8*)&Opart[(slab + q0 + row) * DH + off] =
            *(const bf16x8*)&SMEM[row * 72 + off];
    }
}

// ---------------------------------------------------------------------------
// Kernel 2b: merge split-K partials -> Ctx bf16 [s][E]. (exp2-domain)
// ---------------------------------------------------------------------------
__global__ __launch_bounds__(256) void flash_merge(
    const short* __restrict__ Opart, const float* __restrict__ Mpart,
    const float* __restrict__ Lpart, short* __restrict__ Ctx)
{
    const int row = blockIdx.x * 4 + (threadIdx.x >> 6);
    const int lane = threadIdx.x & 63;
    const int h = row >> 12, q = row & 4095;
    const int nc = (q >> CKL2) + 1;

    float mv[NCHUNK], lv[NCHUNK];
    float M = NEG_BIG;
    #pragma unroll
    for (int c = 0; c < NCHUNK; c++) {
        if (c < nc) {
            mv[c] = Mpart[((size_t)h * NCHUNK + c) * S_LEN + q];
            lv[c] = Lpart[((size_t)h * NCHUNK + c) * S_LEN + q];
            M = fmaxf(M, mv[c]);
        }
    }
    float L = 0.f, O = 0.f;
    #pragma unroll
    for (int c = 0; c < NCHUNK; c++) {
        if (c < nc) {
            const float w = EXP2F(mv[c] - M);
            L += w * lv[c];
            O += w * bf2f(Opart[(((size_t)h * NCHUNK + c) * S_LEN + q) * DH + lane]);
        }
    }
    const float inv = (L > 0.f) ? 1.0f / L : 0.f;
    Ctx[(size_t)q * EMB + h * DH + lane] = f2bf(O * inv);
}

// ---------------------------------------------------------------------------
// Fallback single-pass flash (exp2-domain, Q pre-scaled) if ws too small.
// ---------------------------------------------------------------------------
__global__ __launch_bounds__(256) void flash_attn(
    const short* __restrict__ Qw, const short* __restrict__ Kw,
    const short* __restrict__ Vt, short* __restrict__ Ctx)
{
    __shared__ __align__(16) short Ks[128 * 64];
    __shared__ __align__(16) short Vs[64 * 128];
    __shared__ __align__(16) short Ps[4][32 * 128];

    const int h  = blockIdx.y;
    const int qt = (gridDim.x - 1) - blockIdx.x;
    const int q0 = qt * 128;
    const int t = threadIdx.x;
    const int lane = t & 63, wave = t >> 6;
    const int quad = lane >> 4, l16 = lane & 15;
    const int qw0 = q0 + wave * 32;

    bf16x8 qf[2][2];
    #pragma unroll
    for (int i = 0; i < 2; i++)
        #pragma unroll
        for (int kb = 0; kb < 2; kb++)
            qf[i][kb] = *(const bf16x8*)
                &Qw[((size_t)h * S_LEN + qw0 + i * 16 + l16) * DH + kb * 32 + quad * 8];

    float m_i[2][4], l_i[2][4];
    f32x4 o_acc[2][4] = {};
    #pragma unroll
    for (int i = 0; i < 2; i++)
        #pragma unroll
        for (int r = 0; r < 4; r++) { m_i[i][r] = NEG_BIG; l_i[i][r] = 0.f; }

    for (int kt = 0; kt <= qt; kt++) {
        const int k0 = kt * 128;
        __syncthreads();
        for (int c = t; c < 1024; c += 256) {
            const int row = c >> 3, cc = (c & 7) * 8;
            *(bf16x8*)&Ks[row * 64 + cc] =
                *(const bf16x8*)&Kw[((size_t)h * S_LEN + k0 + row) * DH + cc];
        }
        for (int c = t; c < 1024; c += 256) {
            const int row = c >> 4, cc = (c & 15) * 8;
            *(bf16x8*)&Vs[row * 128 + cc] =
                *(const bf16x8*)&Vt[((size_t)h * DH + row) * S_LEN + k0 + cc];
        }
        __syncthreads();

        f32x4 sf[2][8] = {};
        #pragma unroll
        for (int j = 0; j < 8; j++) {
            #pragma unroll
            for (int kb = 0; kb < 2; kb++) {
                const bf16x8 kf = *(const bf16x8*)
                    &Ks[(j * 16 + l16) * 64 + kb * 32 + quad * 8];
                #pragma unroll
                for (int i = 0; i < 2; i++)
                    sf[i][j] = __builtin_amdgcn_mfma_f32_16x16x32_bf16(
                        qf[i][kb], kf, sf[i][j], 0, 0, 0);
            }
        }

        const bool diag = (kt == qt);
        #pragma unroll
        for (int i = 0; i < 2; i++) {
            if (diag) {
                const int qbase = qw0 + i * 16 + quad * 4;
                const int kbase = k0 + l16;
                #pragma unroll
                for (int j = 0; j < 8; j++)
                    #pragma unroll
                    for (int r = 0; r < 4; r++)
                        if (kbase + j * 16 > qbase + r) sf[i][j][r] = NEG_BIG;
            }
            #pragma unroll
            for (int r = 0; r < 4; r++) {
                float mx = sf[i][0][r];
                #pragma unroll
                for (int j = 1; j < 8; j++) mx = fmaxf(mx, sf[i][j][r]);
                #pragma unroll
                for (int off = 1; off < 16; off <<= 1)
                    mx = fmaxf(mx, __shfl_xor(mx, off, 64));
                const float mnew = fmaxf(m_i[i][r], mx);
                const float alpha = EXP2F(m_i[i][r] - mnew);
                m_i[i][r] = mnew;
                float rs = 0.f;
                #pragma unroll
                for (int j = 0; j < 8; j++) {
                    const float p = EXP2F(sf[i][j][r] - mnew);
                    sf[i][j][r] = p;
                    rs += p;
                }
                #pragma unroll
                for (int off = 1; off < 16; off <<= 1)
                    rs += __shfl_xor(rs, off, 64);
                l_i[i][r] = l_i[i][r] * alpha + rs;
                #pragma unroll
                for (int db = 0; db < 4; db++) o_acc[i][db][r] *= alpha;
            }
            #pragma unroll
            for (int j = 0; j < 8; j++)
                #pragma unroll
                for (int r = 0; r < 4; r++)
                    Ps[wave][(i * 16 + quad * 4 + r) * 128 + j * 16 + l16] =
                        f2bf(sf[i][j][r]);
        }

        #pragma unroll
        for (int kb = 0; kb < 4; kb++) {
            bf16x8 pf[2];
            #pragma unroll
            for (int i = 0; i < 2; i++)
                pf[i] = *(const bf16x8*)
                    &Ps[wave][(i * 16 + l16) * 128 + kb * 32 + quad * 8];
            #pragma unroll
            for (int db = 0; db < 4; db++) {
                const bf16x8 vf = *(const bf16x8*)
                    &Vs[(db * 16 + l16) * 128 + kb * 32 + quad * 8];
                #pragma unroll
                for (int i = 0; i < 2; i++)
                    o_acc[i][db] = __builtin_amdgcn_mfma_f32_16x16x32_bf16(
                        pf[i], vf, o_acc[i][db], 0, 0, 0);
            }
        }
    }

    #pragma unroll
    for (int i = 0; i < 2; i++)
        #pragma unroll
        for (int r = 0; r < 4; r++) {
            const float li = l_i[i][r];
            const float inv = (li > 0.f) ? 1.0f / li : 0.f;
            const int m = qw0 + i * 16 + quad * 4 + r;
            #pragma unroll
            for (int db = 0; db < 4; db++) {
                const int d = db * 16 + l16;
                Ctx[(size_t)m * EMB + h * DH + d] = f2bf(o_acc[i][db][r] * inv);
            }
        }
}

// ---------------------------------------------------------------------------
// Kernel 3: output projection — r14 (PASSED): 64x128 tiles, 384 blocks
// (1.5/CU). Per wave 32m x 64n, acc[2][4]; XCD banding (384 = 8 x 48).
// ---------------------------------------------------------------------------
__global__ __launch_bounds__(256) void out_gemm(
    const short* __restrict__ A, const short* __restrict__ Wb,
    const float* __restrict__ Bias, float* __restrict__ Out)
{
    __shared__ __align__(16) short As[64 * 64];
    __shared__ __align__(16) short Bs[128 * 64];

    const int flat = blockIdx.x;
    const int swz = (flat & 7) * 48 + (flat >> 3);
    const int m0 = (swz / 6) * 64;
    const int n0 = (swz % 6) * 128;
    const int t = threadIdx.x;
    const int lane = t & 63, wave = t >> 6;
    const int quad = lane >> 4, l16 = lane & 15;
    const int wm = (wave >> 1) * 32, wn = (wave & 1) * 64;
    const int srow = lane >> 3, scol = (lane & 7) * 8;

    f32x4 acc[2][4] = {};

    for (int k0 = 0; k0 < EMB; k0 += 64) {
        #pragma unroll
        for (int qd = 0; qd < 2; qd++) {        // A: 8 chunks (64 rows)
            const int chunk = wave * 2 + qd;
            const int row = chunk * 8 + srow;
            gld_lds16(&A[(size_t)(m0 + row) * EMB + k0 + scol], &As[chunk * 512]);
        }
        #pragma unroll
        for (int qd = 0; qd < 4; qd++) {        // B: 16 chunks (128 rows)
            const int chunk = wave * 4 + qd;
            const int row = chunk * 8 + srow;
            gld_lds16(&Wb[(size_t)(n0 + row) * EMB + k0 + scol], &Bs[chunk * 512]);
        }
        __syncthreads();

        #pragma unroll
        for (int kb = 0; kb < 2; kb++) {
            bf16x8 af[2], bfr[4];
            #pragma unroll
            for (int i = 0; i < 2; i++)
                af[i] = *(const bf16x8*)&As[(wm + i * 16 + l16) * 64 + kb * 32 + quad * 8];
            #pragma unroll
            for (int j = 0; j < 4; j++)
                bfr[j] = *(const bf16x8*)&Bs[(wn + j * 16 + l16) * 64 + kb * 32 + quad * 8];
            #pragma unroll
            for (int i = 0; i < 2; i++)
                #pragma unroll
                for (int j = 0; j < 4; j++)
                    acc[i][j] = __builtin_amdgcn_mfma_f32_16x16x32_bf16(
                        af[i], bfr[j], acc[i][j], 0, 0, 0);
        }
        __syncthreads();
    }

    #pragma unroll
    for (int j = 0; j < 4; j++) {
        const int n = n0 + wn + j * 16 + l16;
        const float bias = Bias[n];
        #pragma unroll
        for (int i = 0; i < 2; i++)
            #pragma unroll
            for (int r = 0; r < 4; r++) {
                const int m = m0 + wm + i * 16 + quad * 4 + r;
                Out[(size_t)m * EMB + n] = acc[i][j][r] + bias;
            }
    }
}

// ---------------------------------------------------------------------------
extern "C" void kernel_launch(void* const* d_in, const int* in_sizes, int n_in,
                              void* d_out, int out_size, void* d_ws, size_t ws_size,
                              hipStream_t stream)
{
    (void)in_sizes; (void)n_in; (void)out_size;
    const float* x     = (const float*)d_in[0];
    const float* w_qkv = (const float*)d_in[2];
    const float* b_qkv = (const float*)d_in[3];
    const float* w_out = (const float*)d_in[4];
    const float* b_out = (const float*)d_in[5];
    float* out = (float*)d_out;

    char* ws = (char*)d_ws;
    const size_t SEG = (size_t)NH * S_LEN * DH * sizeof(short);     // 6 MB
    short* Qw  = (short*)(ws);
    short* Kw  = (short*)(ws + SEG);
    short* Vt  = (short*)(ws + 2 * SEG);
    short* Ctx = (short*)(ws + 3 * SEG);
    const size_t OP_OFF = 4 * SEG;
    const size_t OP_SZ  = (size_t)NH * NCHUNK * S_LEN * DH * sizeof(short);
    const size_t ML_SZ  = (size_t)NH * NCHUNK * S_LEN * sizeof(float);
    short* Opart = (short*)(ws + OP_OFF);
    float* Mpart = (float*)(ws + OP_OFF + OP_SZ);
    float* Lpart = (float*)(ws + OP_OFF + OP_SZ + ML_SZ);
    const size_t need = OP_OFF + OP_SZ + 2 * ML_SZ;

    const int XN8 = (S_LEN * EMB) / 8;
    const int WQ8 = (3 * EMB * EMB) / 8;
    const int WO8 = (EMB * EMB) / 8;
    const size_t WO_BYTES = (size_t)EMB * EMB * sizeof(short);
    short* Xb    = (short*)(ws + OP_OFF);
    short* Wqkvb = (short*)(ws + OP_OFF + (size_t)XN8 * 8 * sizeof(short));
    const bool big = ws_size >= need + WO_BYTES;
    short* Woutb = big ? (short*)(ws + need) : (short*)(ws + OP_OFF);

    if (big) {
        const int tot8 = XN8 + WQ8 + WO8;
        cvt3_bf16<<<dim3((tot8 + 255) / 256), 256, 0, stream>>>(
            x, Xb, XN8, w_qkv, Wqkvb, WQ8, w_out, Woutb, WO8);
    } else {
        cvt_bf16<<<dim3((XN8 + 255) / 256), 256, 0, stream>>>(x, Xb, XN8);
        cvt_bf16<<<dim3((WQ8 + 255) / 256), 256, 0, stream>>>(w_qkv, Wqkvb, WQ8);
    }

    qkv_gemm<<<dim3((S_LEN / 64) * ((3 * EMB) / 128)), 256, 0, stream>>>(
        Xb, Wqkvb, b_qkv, Qw, Kw, Vt);

    if (ws_size >= need) {
        flash_partial<<<dim3(960), 256, 0, stream>>>(
            Qw, Kw, Vt, Opart, Mpart, Lpart);
        flash_merge<<<dim3(NH * S_LEN / 4), 256, 0, stream>>>(
            Opart, Mpart, Lpart, Ctx);
    } else {
        flash_attn<<<dim3(S_LEN / 128, NH), 256, 0, stream>>>(Qw, Kw, Vt, Ctx);
    }

    if (!big)
        cvt_bf16<<<dim3((WO8 + 255) / 256), 256, 0, stream>>>(w_out, Woutb, WO8);
    out_gemm<<<dim3((S_LEN / 64) * (EMB / 128)), 256, 0, stream>>>(
        Ctx, Woutb, b_out, out);
}

// Round 19
// 217.102 us; speedup vs baseline: 1.0184x; 1.0184x over previous
//
#include <hip/hip_runtime.h>
#include <hip/hip_bf16.h>

#define S_LEN 4096
#define EMB   768
#define NH    12
#define DH    64
#define NCHUNK 4
#define CKL2   10         // chunk keys = 1024

#define LOG2E 1.44269504088896f

// finite sentinel instead of -INFINITY: safe under fast-math builds
#define NEG_BIG (-1e30f)

// HW 2^x (v_exp_f32); __exp2f does not exist in HIP device code
#define EXP2F(x) __builtin_amdgcn_exp2f(x)

using bf16x8 = __attribute__((ext_vector_type(8))) short;
using bf16x4 = __attribute__((ext_vector_type(4))) short;
using f32x4  = __attribute__((ext_vector_type(4))) float;

__device__ __forceinline__ short f2bf(float f) {
    __hip_bfloat16 h = __float2bfloat16(f);
    short s; __builtin_memcpy(&s, &h, 2); return s;
}
__device__ __forceinline__ float bf2f(short s) {
    __hip_bfloat16 h; __builtin_memcpy(&h, &s, 2);
    return __bfloat162float(h);
}

// pack two f32 -> two bf16 (RNE) in ONE instruction (no builtin on gfx950)
__device__ __forceinline__ unsigned cvt_pk_bf16(float a, float b) {
    unsigned r;
    asm("v_cvt_pk_bf16_f32 %0, %1, %2" : "=v"(r) : "v"(a), "v"(b));
    return r;
}

// async global->LDS, 16B per lane; lds dest = uniform base + lane*16
__device__ __forceinline__ void gld_lds16(const void* g, void* l) {
    __builtin_amdgcn_global_load_lds(
        (const __attribute__((address_space(1))) unsigned int*)g,
        (__attribute__((address_space(3))) unsigned int*)l, 16, 0, 0);
}

__device__ __forceinline__ void cvt8(const float* s, short* d, int i) {
    const float4 a = ((const float4*)s)[i * 2];
    const float4 b = ((const float4*)s)[i * 2 + 1];
    bf16x8 o;
    o[0] = f2bf(a.x); o[1] = f2bf(a.y); o[2] = f2bf(a.z); o[3] = f2bf(a.w);
    o[4] = f2bf(b.x); o[5] = f2bf(b.y); o[6] = f2bf(b.z); o[7] = f2bf(b.w);
    ((bf16x8*)d)[i] = o;
}

// ---------------------------------------------------------------------------
// Kernel 0a/0b: fp32 -> bf16 converts
// ---------------------------------------------------------------------------
__global__ __launch_bounds__(256) void cvt_bf16(
    const float* __restrict__ s, short* __restrict__ d, int n8)
{
    const int i = blockIdx.x * 256 + threadIdx.x;
    if (i < n8) cvt8(s, d, i);
}

__global__ __launch_bounds__(256) void cvt3_bf16(
    const float* __restrict__ x,  short* __restrict__ xb,  int n8x,
    const float* __restrict__ wq, short* __restrict__ wqb, int n8q,
    const float* __restrict__ wo, short* __restrict__ wob, int n8o)
{
    int i = blockIdx.x * 256 + threadIdx.x;
    if (i < n8x) { cvt8(x, xb, i); return; }
    i -= n8x;
    if (i < n8q) { cvt8(wq, wqb, i); return; }
    i -= n8q;
    if (i < n8o) cvt8(wo, wob, i);
}

// ---------------------------------------------------------------------------
// Kernel 1: QKV projection — r14 (PASSED, 218.7-221.1us total config):
// 64x128 tiles, 1152 blocks (4.5/CU). gld_lds staging, XCD banding
// (1152 = 8 x 144), coalesced epilogues. Per wave: 32m x 64n, acc[2][4].
// Q pre-scaled by log2(e) so flash uses exp2 (1 instr).
// ---------------------------------------------------------------------------
__global__ __launch_bounds__(256) void qkv_gemm(
    const short* __restrict__ Xb, const short* __restrict__ Wb,
    const float* __restrict__ Bias,
    short* __restrict__ Qw, short* __restrict__ Kw, short* __restrict__ Vt)
{
    __shared__ __align__(16) short SMEM[64 * 64 + 128 * 64];  // As | Bs (24KB)
    short* As = SMEM;                     // [64 m][64 k]
    short* Bs = SMEM + 64 * 64;           // [128 n][64 k]

    // XCD-chunked decode: 1152 = 8 chunks of 144 = 8 m-rows x 18 n
    const int flat = blockIdx.x;
    const int swz = (flat & 7) * 144 + (flat >> 3);
    const int m0 = (swz / 18) * 64;
    const int n0 = (swz % 18) * 128;
    const int t = threadIdx.x;
    const int lane = t & 63, wave = t >> 6;
    const int quad = lane >> 4, l16 = lane & 15;
    const int wm = (wave >> 1) * 32, wn = (wave & 1) * 64;
    const int srow = lane >> 3, scol = (lane & 7) * 8;

    f32x4 acc[2][4] = {};

    for (int k0 = 0; k0 < EMB; k0 += 64) {
        #pragma unroll
        for (int qd = 0; qd < 2; qd++) {        // A: 8 chunks (64 rows)
            const int chunk = wave * 2 + qd;
            const int row = chunk * 8 + srow;
            gld_lds16(&Xb[(size_t)(m0 + row) * EMB + k0 + scol], &As[chunk * 512]);
        }
        #pragma unroll
        for (int qd = 0; qd < 4; qd++) {        // B: 16 chunks (128 rows)
            const int chunk = wave * 4 + qd;
            const int row = chunk * 8 + srow;
            gld_lds16(&Wb[(size_t)(n0 + row) * EMB + k0 + scol], &Bs[chunk * 512]);
        }
        __syncthreads();

        #pragma unroll
        for (int kb = 0; kb < 2; kb++) {
            bf16x8 af[2], bfr[4];
            #pragma unroll
            for (int i = 0; i < 2; i++)
                af[i] = *(const bf16x8*)&As[(wm + i * 16 + l16) * 64 + kb * 32 + quad * 8];
            #pragma unroll
            for (int j = 0; j < 4; j++)
                bfr[j] = *(const bf16x8*)&Bs[(wn + j * 16 + l16) * 64 + kb * 32 + quad * 8];
            #pragma unroll
            for (int i = 0; i < 2; i++)
                #pragma unroll
                for (int j = 0; j < 4; j++)
                    acc[i][j] = __builtin_amdgcn_mfma_f32_16x16x32_bf16(
                        af[i], bfr[j], acc[i][j], 0, 0, 0);
        }
        __syncthreads();
    }

    const int part = n0 / EMB;           // block-uniform: 0=Q 1=K 2=V

    if (part < 2) {
        // Q/K: LDS [m 64][n 128] restage -> coalesced 16B stores.
        const float qs = (part == 0) ? LOG2E : 1.0f;
        short* dst = (part == 0) ? Qw : Kw;
        #pragma unroll
        for (int j = 0; j < 4; j++) {
            const int nl = wn + j * 16 + l16;
            const float bias = Bias[n0 + nl];
            #pragma unroll
            for (int i = 0; i < 2; i++)
                #pragma unroll
                for (int r = 0; r < 4; r++)
                    SMEM[(wm + i * 16 + quad * 4 + r) * 128 + nl] =
                        f2bf((acc[i][j][r] + bias) * qs);
        }
        __syncthreads();
        #pragma unroll
        for (int c = t; c < 1024; c += 256) {    // 64 m-rows x 16 8-n chunks
            const int m = c >> 4, noff = (c & 15) * 8;
            const int r768 = (n0 + noff) % EMB;  // head-aligned: noff%64 in 8s
            const int h = r768 >> 6, d = r768 & 63;
            *(bf16x8*)&dst[((size_t)h * S_LEN + m0 + m) * DH + d] =
                *(const bf16x8*)&SMEM[m * 128 + noff];
        }
    } else {
        // V: transpose C-tile through LDS T[128 n][64 m], coalesced Vt rows.
        #pragma unroll
        for (int j = 0; j < 4; j++) {
            const int nl = wn + j * 16 + l16;
            const float bias = Bias[n0 + nl];
            #pragma unroll
            for (int i = 0; i < 2; i++) {
                short4 v;
                v.x = f2bf(acc[i][j][0] + bias);
                v.y = f2bf(acc[i][j][1] + bias);
                v.z = f2bf(acc[i][j][2] + bias);
                v.w = f2bf(acc[i][j][3] + bias);
                *(short4*)&SMEM[nl * 64 + wm + i * 16 + quad * 4] = v;
            }
        }
        __syncthreads();
        const int vrow0 = n0 - 2 * EMB;          // Vt row base = h*64+d = r768
        #pragma unroll
        for (int c = t; c < 1024; c += 256) {    // 128 rows x 8 8-m chunks
            const int row = c >> 3, off = (c & 7) * 8;
            *(bf16x8*)&Vt[(size_t)(vrow0 + row) * S_LEN + m0 + off] =
                *(const bf16x8*)&SMEM[row * 64 + off];
        }
    }
}

// ---------------------------------------------------------------------------
// Kernel 2a: split-K flash partial — r11/r16/r18 VERBATIM (PASSED, ~50-56us).
// Weight-sorted 1-D grid, one job per block; __launch_bounds__(256,3).
// r17 bisect: (256,5) miscompiles (absmax 0.738 bit-identical to r15) —
// KEEP (256,3). Launch-bounds occupancy hints are codegen-affecting and
// correctness-risky on this toolchain; verify in isolation.
// ---------------------------------------------------------------------------
__global__ __launch_bounds__(256, 3) void flash_partial(
    const short* __restrict__ Qw, const short* __restrict__ Kw,
    const short* __restrict__ Vt,
    short* __restrict__ Opart, float* __restrict__ Mpart,
    float* __restrict__ Lpart)
{
    // ---- weight-sorted job decode (960 jobs; audited complete/disjoint):
    int qt, h, kc;
    {
        const int job = blockIdx.x;
        if (job < 624) {
            h = job / 52;
            const int r = job % 52;
            if (r < 25)      { kc = 0; qt = 7 + r; }
            else if (r < 42) { kc = 1; qt = 15 + (r - 25); }
            else if (r < 51) { kc = 2; qt = 23 + (r - 42); }
            else             { kc = 3; qt = 31; }
        } else {
            const int j2 = job - 624;
            const int w = 7 - j2 / 48;
            const int r = j2 % 48;
            h = r >> 2; kc = r & 3;
            qt = 8 * kc + w - 1;
        }
    }
    const int q0  = qt * 128;
    const int ks0 = kc << CKL2;
    const int KIT = (1 << CKL2) / 128;   // 8
    const int nk = min(KIT, (q0 >> 7) - KIT * kc + 1);

    // K tile [128 k][64 d] 16KB | V tile [64 d][128 k] 16KB (single buffer)
    __shared__ __align__(16) short SMEM[128 * 64 + 64 * 128];   // 32 KB
    short* Ks = SMEM;
    short* Vs = SMEM + 128 * 64;

    const int t = threadIdx.x;
    const int lane = t & 63, wave = t >> 6;
    const int quad = lane >> 4, l16 = lane & 15;
    const int qw0 = q0 + wave * 32;          // this wave's 32 q rows
    const int swk = (l16 & 7) << 4;          // K read swizzle (bytes, 3 bits)
    const int swv = l16 << 4;                // V read swizzle (bytes, 4 bits)

    const short* Kh = Kw + (size_t)h * S_LEN * DH;
    const short* Vh = Vt + (size_t)h * DH * S_LEN;

    // staging geometry (r3): pre-swizzled global source, linear LDS dest
    const int krow = lane >> 3;                  // K: row-in-chunk 0..7
    const int kcol = ((lane & 7) ^ krow) << 3;   // pre-swizzled col (shorts)
    const int vrow = lane >> 4;                  // V: row-in-chunk 0..3
    const int vsc  = lane & 15;                  // 16B slot in 256B row

    bf16x8 qf[2][2];
    #pragma unroll
    for (int i = 0; i < 2; i++)
        #pragma unroll
        for (int kb = 0; kb < 2; kb++)
            qf[i][kb] = *(const bf16x8*)
                &Qw[((size_t)h * S_LEN + qw0 + i * 16 + l16) * DH + kb * 32 + quad * 8];

    // constant ones-row A-fragment -> row sum via MFMA (5th PV block)
    bf16x8 vfc;
    {
        const short o1 = (l16 == 0) ? (short)0x3F80 : (short)0;
        #pragma unroll
        for (int c = 0; c < 8; c++) vfc[c] = o1;
    }

    float m_i[2] = {NEG_BIG, NEG_BIG};
    f32x4 o_acc[2][5] = {};                  // [i][4] = ones-row -> sum(p)

    for (int kt = 0; kt < nk; kt++) {
        const int k0 = ks0 + kt * 128;

        __syncthreads();                     // prev tile's readers done
        #pragma unroll
        for (int i = 0; i < 4; i++) {
            const int ck = wave * 4 + i;                 // chunk 0..15
            const int rk = ck * 8 + krow;                // K tile row (key)
            gld_lds16(&Kh[(size_t)(k0 + rk) * DH + kcol], &Ks[ck * 512]);
            const int rv = ck * 4 + vrow;                // V tile row (d)
            const int vcol = (vsc ^ (rv & 15)) << 3;
            gld_lds16(&Vh[(size_t)rv * S_LEN + k0 + vcol], &Vs[ck * 512]);
        }
        __syncthreads();                     // drains vmcnt: data landed

        const bool maskn = (k0 + 127 > q0);
        #pragma unroll
        for (int sub = 0; sub < 2; sub++) {
            const int kbase = k0 + sub * 64;
            if (maskn && kbase > qw0 + 31) continue;          // wave masked
            const bool a0 = !(maskn && kbase > qw0 + 15);     // frag0 active

            // ---- QK^T: sfT[i][bb][r] = score(key=kbase+bb*16+quad*4+r,
            //                                  q=qw0+i*16+l16)
            f32x4 sfT[2][4];
            __builtin_amdgcn_s_setprio(1);
            #pragma unroll
            for (int bb = 0; bb < 4; bb++) {
                const int row = (sub * 4 + bb) * 16 + l16;
                bf16x8 kf[2];
                #pragma unroll
                for (int kb = 0; kb < 2; kb++)
                    kf[kb] = *(const bf16x8*)((const char*)Ks
                        + row * 128 + ((kb * 64 + quad * 16) ^ swk));
                sfT[1][bb] = f32x4{};
                #pragma unroll
                for (int kb = 0; kb < 2; kb++)
                    sfT[1][bb] = __builtin_amdgcn_mfma_f32_16x16x32_bf16(
                        kf[kb], qf[1][kb], sfT[1][bb], 0, 0, 0);
                if (a0) {
                    sfT[0][bb] = f32x4{};
                    #pragma unroll
                    for (int kb = 0; kb < 2; kb++)
                        sfT[0][bb] = __builtin_amdgcn_mfma_f32_16x16x32_bf16(
                            kf[kb], qf[0][kb], sfT[0][bb], 0, 0, 0);
                }
            }
            __builtin_amdgcn_s_setprio(0);

            if (maskn) {
                #pragma unroll
                for (int i = 0; i < 2; i++) {
                    if (i == 0 && !a0) continue;
                    const int qg = qw0 + i * 16 + l16;
                    #pragma unroll
                    for (int bb = 0; bb < 4; bb++)
                        #pragma unroll
                        for (int r = 0; r < 4; r++)
                            if (kbase + bb * 16 + quad * 4 + r > qg)
                                sfT[i][bb][r] = NEG_BIG;
                }
            }

            // ---- online softmax per fragment, defer-max (T13, THR=8 log2)
            #pragma unroll
            for (int i = 0; i < 2; i++) {
                if (i == 0 && !a0) continue;
                float mx = sfT[i][0][0];
                #pragma unroll
                for (int bb = 0; bb < 4; bb++)
                    #pragma unroll
                    for (int r = 0; r < 4; r++) mx = fmaxf(mx, sfT[i][bb][r]);
                mx = fmaxf(mx, __shfl_xor(mx, 16, 64));
                mx = fmaxf(mx, __shfl_xor(mx, 32, 64));
                if (!__all(mx <= m_i[i] + 8.0f)) {
                    const float mnew = fmaxf(m_i[i], mx);
                    const float alpha = EXP2F(m_i[i] - mnew);
                    m_i[i] = mnew;
                    #pragma unroll
                    for (int db = 0; db < 5; db++) o_acc[i][db] *= alpha;
                }
                #pragma unroll
                for (int bb = 0; bb < 4; bb++)
                    #pragma unroll
                    for (int r = 0; r < 4; r++)
                        sfT[i][bb][r] = EXP2F(sfT[i][bb][r] - m_i[i]);
            }

            // ---- PV: full-K=32 MFMA; V fragment shared by both q-frags
            __builtin_amdgcn_s_setprio(1);
            #pragma unroll
            for (int bp = 0; bp < 2; bp++) {
                bf16x8 pf[2];
                #pragma unroll
                for (int i = 0; i < 2; i++) {
                    if (i == 0 && !a0) continue;
                    int4 pv;
                    pv.x = (int)cvt_pk_bf16(sfT[i][2 * bp][0],     sfT[i][2 * bp][1]);
                    pv.y = (int)cvt_pk_bf16(sfT[i][2 * bp][2],     sfT[i][2 * bp][3]);
                    pv.z = (int)cvt_pk_bf16(sfT[i][2 * bp + 1][0], sfT[i][2 * bp + 1][1]);
                    pv.w = (int)cvt_pk_bf16(sfT[i][2 * bp + 1][2], sfT[i][2 * bp + 1][3]);
                    pf[i] = __builtin_bit_cast(bf16x8, pv);
                }
                const int colb = (sub * 2 + bp) * 64 + quad * 8;  // lo byte col
                #pragma unroll
                for (int db = 0; db < 4; db++) {
                    const char* vb = (const char*)Vs + (db * 16 + l16) * 256;
                    const int2 lo2 = *(const int2*)(vb + (colb ^ swv));
                    const int2 hi2 = *(const int2*)(vb + ((colb + 32) ^ swv));
                    int4 vi; vi.x = lo2.x; vi.y = lo2.y; vi.z = hi2.x; vi.w = hi2.y;
                    const bf16x8 vf = __builtin_bit_cast(bf16x8, vi);
                    o_acc[1][db] = __builtin_amdgcn_mfma_f32_16x16x32_bf16(
                        vf, pf[1], o_acc[1][db], 0, 0, 0);
                    if (a0)
                        o_acc[0][db] = __builtin_amdgcn_mfma_f32_16x16x32_bf16(
                            vf, pf[0], o_acc[0][db], 0, 0, 0);
                }
                o_acc[1][4] = __builtin_amdgcn_mfma_f32_16x16x32_bf16(
                    vfc, pf[1], o_acc[1][4], 0, 0, 0);
                if (a0)
                    o_acc[0][4] = __builtin_amdgcn_mfma_f32_16x16x32_bf16(
                        vfc, pf[0], o_acc[0][4], 0, 0, 0);
            }
            __builtin_amdgcn_s_setprio(0);
        }
    }

    const size_t slab = ((size_t)h * NCHUNK + kc) * S_LEN;

    #pragma unroll
    for (int i = 0; i < 2; i++)
        if (quad == 0) {
            const int q = qw0 + i * 16 + l16;
            Mpart[slab + q] = m_i[i];
            Lpart[slab + q] = o_acc[i][4][0];      // sum(p) from ones-row
        }

    __syncthreads();
    #pragma unroll
    for (int i = 0; i < 2; i++)
        #pragma unroll
        for (int db = 0; db < 4; db++) {
            short4 pk4;
            pk4.x = f2bf(o_acc[i][db][0]); pk4.y = f2bf(o_acc[i][db][1]);
            pk4.z = f2bf(o_acc[i][db][2]); pk4.w = f2bf(o_acc[i][db][3]);
            *(short4*)&SMEM[(wave * 32 + i * 16 + l16) * 72 + db * 16 + quad * 4] = pk4;
        }
    __syncthreads();
    #pragma unroll
    for (int c = t; c < 1024; c += 256) {          // 128 rows x 8 chunks
        const int row = c >> 3, off = (c & 7) * 8;
        *(bf16x8*)&Opart[(slab + q0 + row) * DH + off] =
            *(const bf16x8*)&SMEM[row * 72 + off];
    }
}

// ---------------------------------------------------------------------------
// Kernel 2b: merge split-K partials -> Ctx bf16 [s][E]. (exp2-domain)
// ---------------------------------------------------------------------------
__global__ __launch_bounds__(256) void flash_merge(
    const short* __restrict__ Opart, const float* __restrict__ Mpart,
    const float* __restrict__ Lpart, short* __restrict__ Ctx)
{
    const int row = blockIdx.x * 4 + (threadIdx.x >> 6);
    const int lane = threadIdx.x & 63;
    const int h = row >> 12, q = row & 4095;
    const int nc = (q >> CKL2) + 1;

    float mv[NCHUNK], lv[NCHUNK];
    float M = NEG_BIG;
    #pragma unroll
    for (int c = 0; c < NCHUNK; c++) {
        if (c < nc) {
            mv[c] = Mpart[((size_t)h * NCHUNK + c) * S_LEN + q];
            lv[c] = Lpart[((size_t)h * NCHUNK + c) * S_LEN + q];
            M = fmaxf(M, mv[c]);
        }
    }
    float L = 0.f, O = 0.f;
    #pragma unroll
    for (int c = 0; c < NCHUNK; c++) {
        if (c < nc) {
            const float w = EXP2F(mv[c] - M);
            L += w * lv[c];
            O += w * bf2f(Opart[(((size_t)h * NCHUNK + c) * S_LEN + q) * DH + lane]);
        }
    }
    const float inv = (L > 0.f) ? 1.0f / L : 0.f;
    Ctx[(size_t)q * EMB + h * DH + lane] = f2bf(O * inv);
}

// ---------------------------------------------------------------------------
// Fallback single-pass flash (exp2-domain, Q pre-scaled) if ws too small.
// ---------------------------------------------------------------------------
__global__ __launch_bounds__(256) void flash_attn(
    const short* __restrict__ Qw, const short* __restrict__ Kw,
    const short* __restrict__ Vt, short* __restrict__ Ctx)
{
    __shared__ __align__(16) short Ks[128 * 64];
    __shared__ __align__(16) short Vs[64 * 128];
    __shared__ __align__(16) short Ps[4][32 * 128];

    const int h  = blockIdx.y;
    const int qt = (gridDim.x - 1) - blockIdx.x;
    const int q0 = qt * 128;
    const int t = threadIdx.x;
    const int lane = t & 63, wave = t >> 6;
    const int quad = lane >> 4, l16 = lane & 15;
    const int qw0 = q0 + wave * 32;

    bf16x8 qf[2][2];
    #pragma unroll
    for (int i = 0; i < 2; i++)
        #pragma unroll
        for (int kb = 0; kb < 2; kb++)
            qf[i][kb] = *(const bf16x8*)
                &Qw[((size_t)h * S_LEN + qw0 + i * 16 + l16) * DH + kb * 32 + quad * 8];

    float m_i[2][4], l_i[2][4];
    f32x4 o_acc[2][4] = {};
    #pragma unroll
    for (int i = 0; i < 2; i++)
        #pragma unroll
        for (int r = 0; r < 4; r++) { m_i[i][r] = NEG_BIG; l_i[i][r] = 0.f; }

    for (int kt = 0; kt <= qt; kt++) {
        const int k0 = kt * 128;
        __syncthreads();
        for (int c = t; c < 1024; c += 256) {
            const int row = c >> 3, cc = (c & 7) * 8;
            *(bf16x8*)&Ks[row * 64 + cc] =
                *(const bf16x8*)&Kw[((size_t)h * S_LEN + k0 + row) * DH + cc];
        }
        for (int c = t; c < 1024; c += 256) {
            const int row = c >> 4, cc = (c & 15) * 8;
            *(bf16x8*)&Vs[row * 128 + cc] =
                *(const bf16x8*)&Vt[((size_t)h * DH + row) * S_LEN + k0 + cc];
        }
        __syncthreads();

        f32x4 sf[2][8] = {};
        #pragma unroll
        for (int j = 0; j < 8; j++) {
            #pragma unroll
            for (int kb = 0; kb < 2; kb++) {
                const bf16x8 kf = *(const bf16x8*)
                    &Ks[(j * 16 + l16) * 64 + kb * 32 + quad * 8];
                #pragma unroll
                for (int i = 0; i < 2; i++)
                    sf[i][j] = __builtin_amdgcn_mfma_f32_16x16x32_bf16(
                        qf[i][kb], kf, sf[i][j], 0, 0, 0);
            }
        }

        const bool diag = (kt == qt);
        #pragma unroll
        for (int i = 0; i < 2; i++) {
            if (diag) {
                const int qbase = qw0 + i * 16 + quad * 4;
                const int kbase = k0 + l16;
                #pragma unroll
                for (int j = 0; j < 8; j++)
                    #pragma unroll
                    for (int r = 0; r < 4; r++)
                        if (kbase + j * 16 > qbase + r) sf[i][j][r] = NEG_BIG;
            }
            #pragma unroll
            for (int r = 0; r < 4; r++) {
                float mx = sf[i][0][r];
                #pragma unroll
                for (int j = 1; j < 8; j++) mx = fmaxf(mx, sf[i][j][r]);
                #pragma unroll
                for (int off = 1; off < 16; off <<= 1)
                    mx = fmaxf(mx, __shfl_xor(mx, off, 64));
                const float mnew = fmaxf(m_i[i][r], mx);
                const float alpha = EXP2F(m_i[i][r] - mnew);
                m_i[i][r] = mnew;
                float rs = 0.f;
                #pragma unroll
                for (int j = 0; j < 8; j++) {
                    const float p = EXP2F(sf[i][j][r] - mnew);
                    sf[i][j][r] = p;
                    rs += p;
                }
                #pragma unroll
                for (int off = 1; off < 16; off <<= 1)
                    rs += __shfl_xor(rs, off, 64);
                l_i[i][r] = l_i[i][r] * alpha + rs;
                #pragma unroll
                for (int db = 0; db < 4; db++) o_acc[i][db][r] *= alpha;
            }
            #pragma unroll
            for (int j = 0; j < 8; j++)
                #pragma unroll
                for (int r = 0; r < 4; r++)
                    Ps[wave][(i * 16 + quad * 4 + r) * 128 + j * 16 + l16] =
                        f2bf(sf[i][j][r]);
        }

        #pragma unroll
        for (int kb = 0; kb < 4; kb++) {
            bf16x8 pf[2];
            #pragma unroll
            for (int i = 0; i < 2; i++)
                pf[i] = *(const bf16x8*)
                    &Ps[wave][(i * 16 + l16) * 128 + kb * 32 + quad * 8];
            #pragma unroll
            for (int db = 0; db < 4; db++) {
                const bf16x8 vf = *(const bf16x8*)
                    &Vs[(db * 16 + l16) * 128 + kb * 32 + quad * 8];
                #pragma unroll
                for (int i = 0; i < 2; i++)
                    o_acc[i][db] = __builtin_amdgcn_mfma_f32_16x16x32_bf16(
                        pf[i], vf, o_acc[i][db], 0, 0, 0);
            }
        }
    }

    #pragma unroll
    for (int i = 0; i < 2; i++)
        #pragma unroll
        for (int r = 0; r < 4; r++) {
            const float li = l_i[i][r];
            const float inv = (li > 0.f) ? 1.0f / li : 0.f;
            const int m = qw0 + i * 16 + quad * 4 + r;
            #pragma unroll
            for (int db = 0; db < 4; db++) {
                const int d = db * 16 + l16;
                Ctx[(size_t)m * EMB + h * DH + d] = f2bf(o_acc[i][db][r] * inv);
            }
        }
}

// ---------------------------------------------------------------------------
// Kernel 3: output projection — r19: 64x64 tiles, 768 blocks = EXACTLY
// 3 x 256 CUs (zero dispatch tail; r14's 384 = 1.5 rounds left half the
// machine idle in round 2). EXONERATED by r17 bisect: r15's failure was
// flash launch_bounds alone (bit-identical absmax), not this kernel.
// Per wave 32m x 32n, acc[2][2]; symmetric A/B staging (8 chunks each);
// XCD banding (768 = 8 x 96). flash stays at proven (256,3).
// ---------------------------------------------------------------------------
__global__ __launch_bounds__(256) void out_gemm(
    const short* __restrict__ A, const short* __restrict__ Wb,
    const float* __restrict__ Bias, float* __restrict__ Out)
{
    __shared__ __align__(16) short As[64 * 64];
    __shared__ __align__(16) short Bs[64 * 64];

    const int flat = blockIdx.x;
    const int swz = (flat & 7) * 96 + (flat >> 3);
    const int m0 = (swz / 12) * 64;
    const int n0 = (swz % 12) * 64;
    const int t = threadIdx.x;
    const int lane = t & 63, wave = t >> 6;
    const int quad = lane >> 4, l16 = lane & 15;
    const int wm = (wave >> 1) * 32, wn = (wave & 1) * 32;
    const int srow = lane >> 3, scol = (lane & 7) * 8;

    f32x4 acc[2][2] = {};

    for (int k0 = 0; k0 < EMB; k0 += 64) {
        #pragma unroll
        for (int qd = 0; qd < 2; qd++) {        // A,B: 8 chunks each (64 rows)
            const int chunk = wave * 2 + qd;
            const int row = chunk * 8 + srow;
            gld_lds16(&A [(size_t)(m0 + row) * EMB + k0 + scol], &As[chunk * 512]);
            gld_lds16(&Wb[(size_t)(n0 + row) * EMB + k0 + scol], &Bs[chunk * 512]);
        }
        __syncthreads();

        #pragma unroll
        for (int kb = 0; kb < 2; kb++) {
            bf16x8 af[2], bfr[2];
            #pragma unroll
            for (int i = 0; i < 2; i++)
                af[i] = *(const bf16x8*)&As[(wm + i * 16 + l16) * 64 + kb * 32 + quad * 8];
            #pragma unroll
            for (int j = 0; j < 2; j++)
                bfr[j] = *(const bf16x8*)&Bs[(wn + j * 16 + l16) * 64 + kb * 32 + quad * 8];
            #pragma unroll
            for (int i = 0; i < 2; i++)
                #pragma unroll
                for (int j = 0; j < 2; j++)
                    acc[i][j] = __builtin_amdgcn_mfma_f32_16x16x32_bf16(
                        af[i], bfr[j], acc[i][j], 0, 0, 0);
        }
        __syncthreads();
    }

    #pragma unroll
    for (int j = 0; j < 2; j++) {
        const int n = n0 + wn + j * 16 + l16;
        const float bias = Bias[n];
        #pragma unroll
        for (int i = 0; i < 2; i++)
            #pragma unroll
            for (int r = 0; r < 4; r++) {
                const int m = m0 + wm + i * 16 + quad * 4 + r;
                Out[(size_t)m * EMB + n] = acc[i][j][r] + bias;
            }
    }
}

// ---------------------------------------------------------------------------
extern "C" void kernel_launch(void* const* d_in, const int* in_sizes, int n_in,
                              void* d_out, int out_size, void* d_ws, size_t ws_size,
                              hipStream_t stream)
{
    (void)in_sizes; (void)n_in; (void)out_size;
    const float* x     = (const float*)d_in[0];
    const float* w_qkv = (const float*)d_in[2];
    const float* b_qkv = (const float*)d_in[3];
    const float* w_out = (const float*)d_in[4];
    const float* b_out = (const float*)d_in[5];
    float* out = (float*)d_out;

    char* ws = (char*)d_ws;
    const size_t SEG = (size_t)NH * S_LEN * DH * sizeof(short);     // 6 MB
    short* Qw  = (short*)(ws);
    short* Kw  = (short*)(ws + SEG);
    short* Vt  = (short*)(ws + 2 * SEG);
    short* Ctx = (short*)(ws + 3 * SEG);
    const size_t OP_OFF = 4 * SEG;
    const size_t OP_SZ  = (size_t)NH * NCHUNK * S_LEN * DH * sizeof(short);
    const size_t ML_SZ  = (size_t)NH * NCHUNK * S_LEN * sizeof(float);
    short* Opart = (short*)(ws + OP_OFF);
    float* Mpart = (float*)(ws + OP_OFF + OP_SZ);
    float* Lpart = (float*)(ws + OP_OFF + OP_SZ + ML_SZ);
    const size_t need = OP_OFF + OP_SZ + 2 * ML_SZ;

    const int XN8 = (S_LEN * EMB) / 8;
    const int WQ8 = (3 * EMB * EMB) / 8;
    const int WO8 = (EMB * EMB) / 8;
    const size_t WO_BYTES = (size_t)EMB * EMB * sizeof(short);
    short* Xb    = (short*)(ws + OP_OFF);
    short* Wqkvb = (short*)(ws + OP_OFF + (size_t)XN8 * 8 * sizeof(short));
    const bool big = ws_size >= need + WO_BYTES;
    short* Woutb = big ? (short*)(ws + need) : (short*)(ws + OP_OFF);

    if (big) {
        const int tot8 = XN8 + WQ8 + WO8;
        cvt3_bf16<<<dim3((tot8 + 255) / 256), 256, 0, stream>>>(
            x, Xb, XN8, w_qkv, Wqkvb, WQ8, w_out, Woutb, WO8);
    } else {
        cvt_bf16<<<dim3((XN8 + 255) / 256), 256, 0, stream>>>(x, Xb, XN8);
        cvt_bf16<<<dim3((WQ8 + 255) / 256), 256, 0, stream>>>(w_qkv, Wqkvb, WQ8);
    }

    qkv_gemm<<<dim3((S_LEN / 64) * ((3 * EMB) / 128)), 256, 0, stream>>>(
        Xb, Wqkvb, b_qkv, Qw, Kw, Vt);

    if (ws_size >= need) {
        flash_partial<<<dim3(960), 256, 0, stream>>>(
            Qw, Kw, Vt, Opart, Mpart, Lpart);
        flash_merge<<<dim3(NH * S_LEN / 4), 256, 0, stream>>>(
            Opart, Mpart, Lpart, Ctx);
    } else {
        flash_attn<<<dim3(S_LEN / 128, NH), 256, 0, stream>>>(Qw, Kw, Vt, Ctx);
    }

    if (!big)
        cvt_bf16<<<dim3((WO8 + 255) / 256), 256, 0, stream>>>(w_out, Woutb, WO8);
    out_gemm<<<dim3((S_LEN / 64) * (EMB / 64)), 256, 0, stream>>>(
        Ctx, Woutb, b_out, out);
}